// Round 5
// baseline (229.826 us; speedup 1.0000x reference)
//
#include <hip/hip_runtime.h>

typedef short bf16x8 __attribute__((ext_vector_type(8)));
typedef float f32x4 __attribute__((ext_vector_type(4)));

#define D 128
#define NROW 98304          // 3 groups * 64 mc * 512 rows
#define X_ELEMS ((size_t)NROW * D)          // bf16 elements in ws
#define NGRID 512                           // fused grid: MUST equal 2 blocks/CU x 256 CU
#define NPTASK 384                          // prep tasks: 192 slices x 2 halves (256 rows)
#define INV_COUNT 5.9604644775390625e-08f   // 1 / (64*512*512)

typedef __attribute__((address_space(3))) void  as3_void;
typedef const __attribute__((address_space(1))) void as1_cvoid;

__device__ __forceinline__ void gl2lds16(const void* g, void* l) {
    __builtin_amdgcn_global_load_lds((as1_cvoid*)g, (as3_void*)l, 16, 0, 0);
}

__device__ __forceinline__ unsigned short f2bf(float f) {
    unsigned u = __float_as_uint(f);
    u += 0x7FFFu + ((u >> 16) & 1u);        // round-to-nearest-even
    return (unsigned short)(u >> 16);
}
__device__ __forceinline__ float bf2f(unsigned short h) {
    return __uint_as_float(((unsigned)h) << 16);
}

// ONE fused kernel: phase P (prep + column-sums) -> device-fenced grid
// barrier (all 512 blocks co-resident BY CONSTRUCTION: launch_bounds(256,2)
// + 66KB LDS caps at exactly 2 blocks/CU, grid = 2*256) -> phase G (GEMM).
// Fusion keeps Xb in L2/L3 between phases instead of a cold HBM round trip,
// and makes the merged dispatch visible in rocprof top-5.
__global__ __launch_bounds__(256, 2) void fused_kernel(
    const float* __restrict__ mu, const float* __restrict__ sigma,
    const float* __restrict__ epsA, const float* __restrict__ epsB,
    const float* __restrict__ epsC,
    unsigned short* __restrict__ Xb, float* __restrict__ sumsq,
    float* __restrict__ pslots, float* __restrict__ Scol,
    float* __restrict__ pssq, unsigned* __restrict__ ctr)
{
    __shared__ unsigned short Bs[2][128 * 128];   // 64 KB (phase P aliases as f32 scratch)
    __shared__ float ssx_s[128];
    __shared__ float ssy_s[512];
    __shared__ float red[4];

    const int bx = blockIdx.x;
    const int t  = threadIdx.x;
    const int wave = t >> 6, lane = t & 63;

    // ================= phase P: prep 256 rows + column sums =================
    if (bx < NPTASK) {
        const int slice = bx >> 1, half = bx & 1;   // slice = g*64+m
        const int g = slice >> 6, m = slice & 63;
        const float* eps = (g == 0) ? epsA : (g == 1) ? epsB : epsC;
        const int ci = t & 31;                  // float4 col group
        const int rg = t >> 5;                  // 8 rows per pass
        float cs0 = 0.f, cs1 = 0.f, cs2 = 0.f, cs3 = 0.f;   // col sums (g!=1)
        float ssacc = 0.f;                      // partial sum of squares
        #pragma unroll 4
        for (int p = 0; p < 32; ++p) {
            const int r = half * 256 + p * 8 + rg;          // n within slice
            const size_t grow = (size_t)slice * 512 + r;    // global Xb row
            float4 e = ((const float4*)(eps + ((size_t)m * 512 + r) * D))[ci];
            float4 u = ((const float4*)(mu    + ((size_t)(g * 512 + r)) * D))[ci];
            float4 s = ((const float4*)(sigma + ((size_t)(g * 512 + r)) * D))[ci];
            unsigned short b0 = f2bf(fmaf(s.x, e.x, u.x));
            unsigned short b1 = f2bf(fmaf(s.y, e.y, u.y));
            unsigned short b2 = f2bf(fmaf(s.z, e.z, u.z));
            unsigned short b3 = f2bf(fmaf(s.w, e.w, u.w));
            float f0 = bf2f(b0), f1 = bf2f(b1), f2 = bf2f(b2), f3 = bf2f(b3);
            float ss = f0 * f0 + f1 * f1 + f2 * f2 + f3 * f3;
            uint2 packed;
            packed.x = (unsigned)b0 | ((unsigned)b1 << 16);
            packed.y = (unsigned)b2 | ((unsigned)b3 << 16);
            ((uint2*)(Xb + grow * D))[ci] = packed;
            ssacc += ss;
            if (g != 1) { cs0 += f0; cs1 += f1; cs2 += f2; cs3 += f3; }
            float sr = ss;
            #pragma unroll
            for (int o = 16; o > 0; o >>= 1) sr += __shfl_down(sr, o, 32);
            if (ci == 0) sumsq[grow] = sr;
        }
        if (g != 1) {   // block-uniform branch: barriers legal
            float* cfs = (float*)Bs;            // [8][128] scratch
            __syncthreads();
            cfs[rg * 128 + ci * 4 + 0] = cs0;
            cfs[rg * 128 + ci * 4 + 1] = cs1;
            cfs[rg * 128 + ci * 4 + 2] = cs2;
            cfs[rg * 128 + ci * 4 + 3] = cs3;
            __syncthreads();
            if (t < 128) {
                float sc = 0.f;
                #pragma unroll
                for (int rr = 0; rr < 8; ++rr) sc += cfs[rr * 128 + t];
                Scol[((g == 0 ? 0 : 128) + m * 2 + half) * 128 + t] = sc;
            }
            float sa = ssacc;
            #pragma unroll
            for (int o = 32; o > 0; o >>= 1) sa += __shfl_down(sa, o, 64);
            if (lane == 0) red[wave] = sa;
            __syncthreads();
            if (t == 0) pssq[bx] = red[0] + red[1] + red[2] + red[3];
        }
    }

    // ================= device-scope grid barrier =================
    __threadfence();                            // release: flush this block's stores
    __syncthreads();
    if (t == 0) {
        atomicAdd(&ctr[0], 1u);                 // device-scope by default
        while (__hip_atomic_load(&ctr[0], __ATOMIC_RELAXED,
                                 __HIP_MEMORY_SCOPE_AGENT) < NGRID)
            __builtin_amdgcn_s_sleep(2);
    }
    __syncthreads();
    __threadfence();                            // acquire: invalidate stale caches

    // ================= phase G: GEMM strip (dist,m,tn) =================
    const int xcd = bx & 7;
    const int idx = bx >> 3;                  // 0..63
    const int tn  = idx & 3;                  // A row-strip within slice
    const int dl  = (idx >> 2) & 1;           // 0 -> dBA, 1 -> dBC
    const int mh  = idx >> 3;                 // 0..7
    const int m   = xcd + mh * 8;             // m % 8 == xcd  (L2 locality)
    const int gy  = dl ? 2 : 0;               // y group: A or C; x is always B(1)

    const char* Xa = (const char*)(Xb + (((size_t)(64 + m)) * 512 + tn * 128) * D);
    const char* Xc = (const char*)(Xb + (((size_t)(gy * 64 + m)) * 512) * D);
    const float* ssx = sumsq + ((size_t)(64 + m)) * 512 + tn * 128;
    const float* ssy = sumsq + ((size_t)(gy * 64 + m)) * 512;

    const int wr = (wave >> 1) * 64;          // wave's 64x64 quadrant rows
    const int wc = (wave & 1) * 64;
    const int l15 = lane & 15, quad = lane >> 4;

    // full-K (256B) row staging: 4 rows per 1KB instr; XOR-swizzled GLOBAL
    // source, linear LDS (proven pattern). lds[row][s] = glob[row][s^(row&7)]
    const int sr4 = lane >> 4;                // row within the 4-row instr
    const int sg  = lane & 15;                // 16B slot within row

    if (t < 128) ssx_s[t] = ssx[t];
    ssy_s[t] = ssy[t];
    ssy_s[t + 256] = ssy[t + 256];

    // A operand global->regs (verified R3/R4: row=wr+fr*16+l15, gran=ks*4+quad)
    bf16x8 aF0[2][4], aF1[2][4];
    #pragma unroll
    for (int ks = 0; ks < 2; ks++)
        #pragma unroll
        for (int fr = 0; fr < 4; fr++) {
            const char* rp = Xa + (wr + fr * 16 + l15) * 256 + (ks * 4 + quad) * 16;
            aF0[ks][fr] = *(const bf16x8*)rp;
            aF1[ks][fr] = *(const bf16x8*)(rp + 128);
        }

    // stage B chunk 0 (rows [0,128), full K)
    #pragma unroll
    for (int i2 = 0; i2 < 8; i2++) {
        const int r0l = wave * 32 + i2 * 4;
        const int grow = r0l + sr4;
        gl2lds16(Xc + (size_t)grow * 256 + ((sg ^ (grow & 7)) * 16), &Bs[0][r0l * 128]);
    }
    __syncthreads();

    f32x4 acc[4][4] = {};
    float lsum = 0.f;

    for (int tk = 0; tk < 4; ++tk) {
        const int buf = tk & 1;
        if (tk < 3) {   // prefetch next full-K chunk into the other buffer
            #pragma unroll
            for (int i2 = 0; i2 < 8; i2++) {
                const int r0l = wave * 32 + i2 * 4;
                const int grow = (tk + 1) * 128 + r0l + sr4;
                gl2lds16(Xc + (size_t)grow * 256 + ((sg ^ (grow & 7)) * 16),
                         &Bs[buf ^ 1][r0l * 128]);
            }
        }

        bf16x8 b0[2][4], b1[2][4];  // [ks][fc] for K-half 0 / 1
        #pragma unroll
        for (int ks = 0; ks < 2; ks++)
            #pragma unroll
            for (int fc = 0; fc < 4; fc++) {
                const int row = wc + fc * 16 + l15;
                const int g0 = ks * 4 + quad;         // K-half 0 granule
                const int g1 = 8 + ks * 4 + quad;     // K-half 1 granule
                b0[ks][fc] = *(const bf16x8*)&Bs[buf][row * 128 + ((g0 ^ (row & 7)) * 8)];
                b1[ks][fc] = *(const bf16x8*)&Bs[buf][row * 128 + ((g1 ^ (row & 7)) * 8)];
            }

        #pragma unroll
        for (int ks = 0; ks < 2; ks++)
            #pragma unroll
            for (int fr = 0; fr < 4; fr++)
                #pragma unroll
                for (int fc = 0; fc < 4; fc++)
                    acc[fr][fc] = __builtin_amdgcn_mfma_f32_16x16x32_bf16(
                        aF0[ks][fr], b0[ks][fc], acc[fr][fc], 0, 0, 0);
        #pragma unroll
        for (int ks = 0; ks < 2; ks++)
            #pragma unroll
            for (int fr = 0; fr < 4; fr++)
                #pragma unroll
                for (int fc = 0; fc < 4; fc++)
                    acc[fr][fc] = __builtin_amdgcn_mfma_f32_16x16x32_bf16(
                        aF1[ks][fr], b1[ks][fc], acc[fr][fc], 0, 0, 0);

        // epilogue for tile tk; C layout: col=lane&15, row=quad*4+i
        #pragma unroll
        for (int fc = 0; fc < 4; fc++) {
            float y2 = ssy_s[tk * 128 + wc + fc * 16 + l15];
            #pragma unroll
            for (int fr = 0; fr < 4; fr++) {
                float d2v[4];
                #pragma unroll
                for (int ii = 0; ii < 4; ii++) {
                    float x2 = ssx_s[wr + fr * 16 + quad * 4 + ii];
                    d2v[ii] = fmaf(-2.f, acc[fr][fc][ii], x2 + y2);
                }
                float mn = fminf(fminf(d2v[0], d2v[1]), fminf(d2v[2], d2v[3]));
                if (__any(mn < 4.f)) {        // relu(M-d) nonzero is rare
                    #pragma unroll
                    for (int ii = 0; ii < 4; ii++) {
                        if (d2v[ii] < 4.f) {
                            float td = 2.f - sqrtf(fmaxf(d2v[ii], 1e-12f));
                            lsum += td * td;
                        }
                    }
                }
                #pragma unroll
                for (int ii = 0; ii < 4; ii++) acc[fr][fc][ii] = 0.f;
            }
        }
        __syncthreads();                      // next buffer staged; reads done
    }

    #pragma unroll
    for (int o = 32; o > 0; o >>= 1) lsum += __shfl_down(lsum, o, 64);
    if (lane == 0) red[wave] = lsum;
    __syncthreads();
    if (t == 0)
        pslots[bx] = red[0] + red[1] + red[2] + red[3];
}

// Final reduction: neg partials (512) + closed-form pos term from
// column sums:  sum d2_AC = sum_m [512*(ss_A+ss_C) - 2*dot(SA_m,SC_m)].
__global__ __launch_bounds__(256) void reduce_kernel(
    const float* __restrict__ pslots, const float* __restrict__ Scol,
    const float* __restrict__ pssq, float* __restrict__ out)
{
    const int t = threadIdx.x;
    float s = pslots[t] + pslots[t + 256];
    if (t < 128) s += 512.f * (pssq[t] + pssq[t + 256]);   // g0 + g2 ss partials
    float dot = 0.f;
    #pragma unroll 8
    for (int k = 0; k < 32; ++k) {            // 8192 (m,d) pairs / 256 threads
        const int p = t + k * 256;
        const int m = p >> 7, d = p & 127;
        float SA = Scol[(m * 2) * 128 + d]       + Scol[(m * 2 + 1) * 128 + d];
        float SC = Scol[(128 + m * 2) * 128 + d] + Scol[(128 + m * 2 + 1) * 128 + d];
        dot += SA * SC;
    }
    s -= 2.f * dot;
    #pragma unroll
    for (int o = 32; o > 0; o >>= 1) s += __shfl_down(s, o, 64);
    __shared__ float red[4];
    const int wave = t >> 6, lane = t & 63;
    if (lane == 0) red[wave] = s;
    __syncthreads();
    if (t == 0) out[0] = (red[0] + red[1] + red[2] + red[3]) * INV_COUNT;
}

extern "C" void kernel_launch(void* const* d_in, const int* in_sizes, int n_in,
                              void* d_out, int out_size, void* d_ws, size_t ws_size,
                              hipStream_t stream) {
    const float* mu    = (const float*)d_in[0];
    const float* sigma = (const float*)d_in[1];
    const float* epsA  = (const float*)d_in[2];
    const float* epsB  = (const float*)d_in[3];
    const float* epsC  = (const float*)d_in[4];
    float* out = (float*)d_out;

    unsigned short* Xb = (unsigned short*)d_ws;              // 25.17 MB bf16
    float* sumsq  = (float*)((char*)d_ws + X_ELEMS * sizeof(unsigned short));
    float* pslots = sumsq + NROW;           // 512 f
    float* Scol   = pslots + 512;           // 256 slots x 128 f = 128 KB
    float* pssq   = Scol + 256 * 128;       // 384 f
    unsigned* ctr = (unsigned*)(pssq + 384);// 8 B barrier counters

    hipMemsetAsync(ctr, 0, 8, stream);      // ws is poisoned each iteration

    fused_kernel<<<NGRID, 256, 0, stream>>>(mu, sigma, epsA, epsB, epsC,
                                            Xb, sumsq, pslots, Scol, pssq, ctr);

    reduce_kernel<<<1, 256, 0, stream>>>(pslots, Scol, pssq, out);
}

// Round 6
// 114.924 us; speedup vs baseline: 1.9998x; 1.9998x over previous
//
#include <hip/hip_runtime.h>

typedef short bf16x8 __attribute__((ext_vector_type(8)));
typedef float f32x4 __attribute__((ext_vector_type(4)));

#define D 128
#define NROW 98304          // 3 groups * 64 mc * 512 rows
#define X_ELEMS ((size_t)NROW * D)          // bf16 elements in ws
#define NBLK 256                            // one block per (dist, m, x-half)
#define INV_COUNT 5.9604644775390625e-08f   // 1 / (64*512*512)

typedef __attribute__((address_space(3))) void  as3_void;
typedef const __attribute__((address_space(1))) void as1_cvoid;

__device__ __forceinline__ void gl2lds16(const void* g, void* l) {
    __builtin_amdgcn_global_load_lds((as1_cvoid*)g, (as3_void*)l, 16, 0, 0);
}

__device__ __forceinline__ unsigned short f2bf(float f) {
    unsigned u = __float_as_uint(f);
    u += 0x7FFFu + ((u >> 16) & 1u);        // round-to-nearest-even
    return (unsigned short)(u >> 16);
}
__device__ __forceinline__ float bf2f(unsigned short h) {
    return __uint_as_float(((unsigned)h) << 16);
}

// 8 rows per block; 32 threads per row: float4 loads, 8B bf16 store,
// width-32 shuffle reduce for sum(x_bf16^2).  (round-0 proven version)
__global__ __launch_bounds__(256) void prep_kernel(
    const float* __restrict__ mu, const float* __restrict__ sigma,
    const float* __restrict__ epsA, const float* __restrict__ epsB,
    const float* __restrict__ epsC,
    unsigned short* __restrict__ Xb, float* __restrict__ sumsq)
{
    int t = threadIdx.x;
    int row  = blockIdx.x * 8 + (t >> 5);   // 0..NROW-1
    int ci   = t & 31;                      // float4 index within row
    int n  = row & 511;
    int gm = row >> 9;        // g*64 + m
    int g  = gm >> 6;
    int m  = gm & 63;
    const float* eps = (g == 0) ? epsA : (g == 1) ? epsB : epsC;
    float4 e = ((const float4*)(eps + ((size_t)m * 512 + n) * D))[ci];
    float4 u = ((const float4*)(mu    + ((size_t)(g * 512 + n)) * D))[ci];
    float4 s = ((const float4*)(sigma + ((size_t)(g * 512 + n)) * D))[ci];
    unsigned short b0 = f2bf(fmaf(s.x, e.x, u.x));
    unsigned short b1 = f2bf(fmaf(s.y, e.y, u.y));
    unsigned short b2 = f2bf(fmaf(s.z, e.z, u.z));
    unsigned short b3 = f2bf(fmaf(s.w, e.w, u.w));
    float f0 = bf2f(b0), f1 = bf2f(b1), f2 = bf2f(b2), f3 = bf2f(b3);
    float ss = f0 * f0 + f1 * f1 + f2 * f2 + f3 * f3;
    uint2 packed;
    packed.x = (unsigned)b0 | ((unsigned)b1 << 16);
    packed.y = (unsigned)b2 | ((unsigned)b3 << 16);
    ((uint2*)(Xb + (size_t)row * D))[ci] = packed;
    #pragma unroll
    for (int o = 16; o > 0; o >>= 1) ss += __shfl_down(ss, o, 32);
    if (ci == 0) sumsq[row] = ss;
}

// 256 blocks, 512 threads, ~100 KB LDS -> exactly 1 block/CU, whole GPU.
// Block (dist, m, xh): output strip 256 x-rows (X_B half) x 512 y-rows.
// A staged ONCE (64 KB) then per-wave in regs; y streamed once through a
// 16 KB double buffer in 8 chunks. Logical fetch/block = 192 KB -> 48 MB
// total (vs 201 MB in R0) against the measured ~4.3 TB/s L3 ceiling.
// xh==0 blocks also compute column sums of their y-stream (X_A or X_C)
// for the closed-form pos term, and fold 512*sum(ssy) into lsum.
__global__ __launch_bounds__(512, 2) void dist_kernel(
    const unsigned short* __restrict__ Xb, const float* __restrict__ sumsq,
    float* __restrict__ pslots, float* __restrict__ Scol)
{
    __shared__ unsigned short As_l[256 * 128];      // 64 KB, full-K A half
    __shared__ unsigned short Bs_l[2][64 * 128];    // 32 KB, y chunk dbuf
    __shared__ float ssx_s[256];
    __shared__ float ssy_s[512];
    __shared__ float red[8];

    const int bx = blockIdx.x;
    const int t  = threadIdx.x;
    const int wave = t >> 6, lane = t & 63;

    const int xcd = bx & 7;
    const int mh  = (bx >> 3) & 7;
    const int m   = xcd + mh * 8;             // m % 8 == xcd (L2 affinity)
    const int q   = bx >> 6;                  // 0..3
    const int dist = q & 1;                   // 0 -> dBA (y=A), 1 -> dBC (y=C)
    const int xh   = q >> 1;                  // which 256-row half of X_B
    const int gy   = dist ? 2 : 0;

    const char* Xa = (const char*)(Xb + (((size_t)(64 + m)) * 512 + xh * 256) * D);
    const char* Xc = (const char*)(Xb + ((size_t)(gy * 64 + m)) * 512 * D);
    const float* ssx = sumsq + ((size_t)(64 + m)) * 512 + xh * 256;
    const float* ssy = sumsq + ((size_t)(gy * 64 + m)) * 512;

    const int xg = wave >> 1, yc = wave & 1;  // 4 x-groups x 2 y-halves
    const int l15 = lane & 15, quad = lane >> 4;
    const int sr4 = lane >> 4, sg = lane & 15;    // staging: 4 rows x 16 slots

    if (t < 256) ssx_s[t] = ssx[t];
    ssy_s[t] = ssy[t];

    // ---- stage A half (256 rows, full K): XOR-preswizzled global source,
    // linear LDS (byte-identical to the R5-verified pattern) ----
    #pragma unroll
    for (int i = 0; i < 8; i++) {
        const int r0l = wave * 32 + i * 4;
        const int grow = r0l + sr4;
        gl2lds16(Xa + (size_t)grow * 256 + ((sg ^ (grow & 7)) * 16), &As_l[r0l * 128]);
    }
    // ---- stage y chunk 0 (64 rows) ----
    #pragma unroll
    for (int i = 0; i < 2; i++) {
        const int r0l = wave * 8 + i * 4;
        const int grow = r0l + sr4;
        gl2lds16(Xc + (size_t)grow * 256 + ((sg ^ (grow & 7)) * 16), &Bs_l[0][r0l * 128]);
    }
    __syncthreads();

    // ---- wave's A operand (64 rows x K=128) LDS -> regs, all-static ----
    bf16x8 aF[4][4];
    #pragma unroll
    for (int kk = 0; kk < 4; kk++)
        #pragma unroll
        for (int fr = 0; fr < 4; fr++) {
            const int row = xg * 64 + fr * 16 + l15;
            aF[kk][fr] = *(const bf16x8*)&As_l[row * 128 +
                                              (((kk * 4 + quad) ^ (row & 7)) * 8)];
        }

    f32x4 acc[4][2] = {};
    float lsum = (xh == 0) ? 512.f * ssy_s[t] : 0.f;   // pos-term ssq fold
    float cs = 0.f;                                    // colsum partial
    const int ccol = t & 127, crq = t >> 7;            // col, row-quarter
    const int cg = ccol >> 3, ce = ccol & 7;

    #pragma unroll 1
    for (int c = 0; c < 8; ++c) {
        const unsigned short* bb = Bs_l[c & 1];
        if (c < 7) {    // prefetch next chunk into the other buffer
            #pragma unroll
            for (int i = 0; i < 2; i++) {
                const int r0l = wave * 8 + i * 4;
                const int grow = (c + 1) * 64 + r0l + sr4;
                gl2lds16(Xc + (size_t)grow * 256 + ((sg ^ (grow & 7)) * 16),
                         &Bs_l[(c & 1) ^ 1][r0l * 128]);
            }
        }

        // MFMA: wave tile 64x (xg) x 32y (yc-half of the 64-row chunk)
        #pragma unroll
        for (int kk = 0; kk < 4; kk++) {
            bf16x8 b[2];
            #pragma unroll
            for (int fc = 0; fc < 2; fc++) {
                const int row = yc * 32 + fc * 16 + l15;
                b[fc] = *(const bf16x8*)&bb[row * 128 +
                                            (((kk * 4 + quad) ^ (row & 7)) * 8)];
            }
            #pragma unroll
            for (int fr = 0; fr < 4; fr++)
                #pragma unroll
                for (int fc = 0; fc < 2; fc++)
                    acc[fr][fc] = __builtin_amdgcn_mfma_f32_16x16x32_bf16(
                        aF[kk][fr], b[fc], acc[fr][fc], 0, 0, 0);
        }

        // column sums of the y-stream (pos term), xh==0 blocks only
        if (xh == 0) {
            #pragma unroll 8
            for (int rr = 0; rr < 16; ++rr) {
                const int r = crq * 16 + rr;
                cs += bf2f(bb[r * 128 + ((cg ^ (r & 7)) * 8) + ce]);
            }
        }

        // epilogue for chunk c; C layout: col=lane&15, row=quad*4+ii
        #pragma unroll
        for (int fc = 0; fc < 2; fc++) {
            float y2 = ssy_s[c * 64 + yc * 32 + fc * 16 + l15];
            #pragma unroll
            for (int fr = 0; fr < 4; fr++) {
                float d2v[4];
                #pragma unroll
                for (int ii = 0; ii < 4; ii++) {
                    float x2 = ssx_s[xg * 64 + fr * 16 + quad * 4 + ii];
                    d2v[ii] = fmaf(-2.f, acc[fr][fc][ii], x2 + y2);
                }
                float mn = fminf(fminf(d2v[0], d2v[1]), fminf(d2v[2], d2v[3]));
                if (__any(mn < 4.f)) {        // relu(M-d) nonzero is rare
                    #pragma unroll
                    for (int ii = 0; ii < 4; ii++) {
                        if (d2v[ii] < 4.f) {
                            float td = 2.f - sqrtf(fmaxf(d2v[ii], 1e-12f));
                            lsum += td * td;
                        }
                    }
                }
                #pragma unroll
                for (int ii = 0; ii < 4; ii++) acc[fr][fc][ii] = 0.f;
            }
        }
        __syncthreads();    // next chunk staged; bb reads (incl colsum) done
    }

    #pragma unroll
    for (int o = 32; o > 0; o >>= 1) lsum += __shfl_down(lsum, o, 64);
    if (lane == 0) red[wave] = lsum;
    __syncthreads();

    if (xh == 0) {          // block-uniform branch: barriers legal
        float* part = (float*)Bs_l;         // reuse (all reads complete)
        part[t] = cs;
        __syncthreads();
        if (t < 128)
            Scol[dist * 8192 + m * 128 + t] =
                part[t] + part[t + 128] + part[t + 256] + part[t + 384];
    }
    if (t == 0) {
        float s = 0.f;
        #pragma unroll
        for (int w = 0; w < 8; ++w) s += red[w];
        pslots[bx] = s;
    }
}

// Final reduction: 256 neg/ssq partials + closed-form pos dot:
//   total -= 2 * sum_m <S_A[m], S_C[m]>
__global__ __launch_bounds__(256) void reduce_kernel(
    const float* __restrict__ pslots, const float* __restrict__ Scol,
    float* __restrict__ out)
{
    const int t = threadIdx.x;
    float s = pslots[t];
    float dot = 0.f;
    #pragma unroll 8
    for (int k = 0; k < 32; ++k) {            // 8192 (m,d) pairs / 256 threads
        const int p = t + k * 256;
        dot += Scol[p] * Scol[8192 + p];
    }
    s -= 2.f * dot;
    #pragma unroll
    for (int o = 32; o > 0; o >>= 1) s += __shfl_down(s, o, 64);
    __shared__ float red[4];
    const int wave = t >> 6, lane = t & 63;
    if (lane == 0) red[wave] = s;
    __syncthreads();
    if (t == 0) out[0] = (red[0] + red[1] + red[2] + red[3]) * INV_COUNT;
}

extern "C" void kernel_launch(void* const* d_in, const int* in_sizes, int n_in,
                              void* d_out, int out_size, void* d_ws, size_t ws_size,
                              hipStream_t stream) {
    const float* mu    = (const float*)d_in[0];
    const float* sigma = (const float*)d_in[1];
    const float* epsA  = (const float*)d_in[2];
    const float* epsB  = (const float*)d_in[3];
    const float* epsC  = (const float*)d_in[4];
    float* out = (float*)d_out;

    unsigned short* Xb = (unsigned short*)d_ws;              // 25.17 MB bf16
    float* sumsq  = (float*)((char*)d_ws + X_ELEMS * sizeof(unsigned short));
    float* pslots = sumsq + NROW;           // 256 f
    float* Scol   = pslots + 256;           // 2 x 64 x 128 f = 64 KB

    prep_kernel<<<NROW / 8, 256, 0, stream>>>(mu, sigma, epsA, epsB, epsC, Xb, sumsq);

    dist_kernel<<<NBLK, 512, 0, stream>>>(Xb, sumsq, pslots, Scol);

    reduce_kernel<<<1, 256, 0, stream>>>(pslots, Scol, out);
}